// Round 1
// baseline (18593.459 us; speedup 1.0000x reference)
//
#include <hip/hip_runtime.h>
#include <math.h>

#define N_NODES 100000
#define N_EDGES 3200000

// ---------------------------------------------------------------------------
// Tiled fp32 GEMM: out[M x N] = X[M x K] @ W[K x N] + bias, optional ReLU on X
// BM=64, BN=64, BK=16; block 256 threads; 4x4 register tile per thread.
// ---------------------------------------------------------------------------
template<bool RELU>
__global__ __launch_bounds__(256) void gemm_kernel(
    const float* __restrict__ X, const float* __restrict__ W,
    const float* __restrict__ bias, float* __restrict__ out,
    int M, int K, int N) {
  constexpr int BM = 64, BN = 64, BK = 16;
  __shared__ float xs[BK][BM + 4];  // transposed X tile, stride 68 (2-way only)
  __shared__ float ws[BK][BN];      // W tile

  const int tid = threadIdx.x;
  const int bm = blockIdx.x * BM;
  const int bn = blockIdx.y * BN;
  const int tx = tid & 15;   // col group: cols bn + tx*4 .. +3
  const int ty = tid >> 4;   // row group: rows bm + ty*4 .. +3

  // loader indices
  const int lr = tid >> 2;   // X: row within tile (0..63)
  const int lq = tid & 3;    // X: k-quad (0..3)
  const int wk = tid >> 4;   // W: k within tile (0..15)
  const int wq = tid & 15;   // W: col-quad (0..15)

  float acc[4][4] = {{0.f}};

  for (int k0 = 0; k0 < K; k0 += BK) {
    // --- load X tile (64 rows x 16 k), transpose into xs[k][m] ---
    {
      int row = bm + lr;
      float4 v = make_float4(0.f, 0.f, 0.f, 0.f);
      if (row < M) v = *(const float4*)(X + (size_t)row * K + k0 + lq * 4);
      if (RELU) {
        v.x = fmaxf(v.x, 0.f); v.y = fmaxf(v.y, 0.f);
        v.z = fmaxf(v.z, 0.f); v.w = fmaxf(v.w, 0.f);
      }
      xs[lq * 4 + 0][lr] = v.x;
      xs[lq * 4 + 1][lr] = v.y;
      xs[lq * 4 + 2][lr] = v.z;
      xs[lq * 4 + 3][lr] = v.w;
    }
    // --- load W tile (16 k x 64 cols) ---
    {
      int col = bn + wq * 4;
      float4 v = make_float4(0.f, 0.f, 0.f, 0.f);
      if (col < N) v = *(const float4*)(W + (size_t)(k0 + wk) * N + col);
      *(float4*)&ws[wk][wq * 4] = v;
    }
    __syncthreads();

    #pragma unroll
    for (int kk = 0; kk < BK; ++kk) {
      float4 xv = *(const float4*)&xs[kk][ty * 4];
      float4 wv = *(const float4*)&ws[kk][tx * 4];
      acc[0][0] += xv.x * wv.x; acc[0][1] += xv.x * wv.y;
      acc[0][2] += xv.x * wv.z; acc[0][3] += xv.x * wv.w;
      acc[1][0] += xv.y * wv.x; acc[1][1] += xv.y * wv.y;
      acc[1][2] += xv.y * wv.z; acc[1][3] += xv.y * wv.w;
      acc[2][0] += xv.z * wv.x; acc[2][1] += xv.z * wv.y;
      acc[2][2] += xv.z * wv.z; acc[2][3] += xv.z * wv.w;
      acc[3][0] += xv.w * wv.x; acc[3][1] += xv.w * wv.y;
      acc[3][2] += xv.w * wv.z; acc[3][3] += xv.w * wv.w;
    }
    __syncthreads();
  }

  // --- epilogue: add bias, store ---
  const int col0 = bn + tx * 4;
  #pragma unroll
  for (int i = 0; i < 4; ++i) {
    int row = bm + ty * 4 + i;
    if (row < M) {
      #pragma unroll
      for (int j = 0; j < 4; ++j) {
        int col = col0 + j;
        if (col < N) out[(size_t)row * N + col] = acc[i][j] + bias[col];
      }
    }
  }
}

// ---------------------------------------------------------------------------
// Edge-parallel SpMM: h[dst] += val * s[src], atomicAdd per float.
// One thread handles one edge x one float4 of features.
// D: feature width, QL: log2(threads per edge), NQ: active quads per edge.
// ---------------------------------------------------------------------------
template<int D, int QL, int NQ>
__global__ __launch_bounds__(256) void spmm_kernel(
    const int* __restrict__ esrc, const int* __restrict__ edst,
    const float* __restrict__ eval, const float* __restrict__ s,
    float* __restrict__ h) {
  const long long idx = (long long)blockIdx.x * 256 + threadIdx.x;
  const int e = (int)(idx >> QL);
  const int q = (int)(idx & ((1 << QL) - 1));
  if (NQ < (1 << QL) && q >= NQ) return;
  const int src = esrc[e];
  const int dst = edst[e];
  const float val = eval[e];
  const float4 sv = *(const float4*)(s + (size_t)src * D + q * 4);
  float* hp = h + (size_t)dst * D + q * 4;
  atomicAdd(hp + 0, val * sv.x);
  atomicAdd(hp + 1, val * sv.y);
  atomicAdd(hp + 2, val * sv.z);
  atomicAdd(hp + 3, val * sv.w);
}

// ---------------------------------------------------------------------------
// Row-wise log_softmax over 40 classes; one wave (64 lanes) per row, in-place.
// ---------------------------------------------------------------------------
__global__ __launch_bounds__(256) void logsoftmax_kernel(float* __restrict__ io,
                                                         int M) {
  const int lane = threadIdx.x & 63;
  const int row = blockIdx.x * 4 + (threadIdx.x >> 6);
  if (row >= M) return;
  float v = (lane < 40) ? io[(size_t)row * 40 + lane] : -INFINITY;
  float m = v;
  #pragma unroll
  for (int off = 32; off > 0; off >>= 1)
    m = fmaxf(m, __shfl_xor(m, off));
  float ex = (lane < 40) ? __expf(v - m) : 0.f;
  float sum = ex;
  #pragma unroll
  for (int off = 32; off > 0; off >>= 1)
    sum += __shfl_xor(sum, off);
  if (lane < 40) io[(size_t)row * 40 + lane] = v - m - logf(sum);
}

// ---------------------------------------------------------------------------
extern "C" void kernel_launch(void* const* d_in, const int* in_sizes, int n_in,
                              void* d_out, int out_size, void* d_ws,
                              size_t ws_size, hipStream_t stream) {
  const float* x    = (const float*)d_in[0];
  const int*   esrc = (const int*)d_in[1];
  const int*   edst = (const int*)d_in[2];
  const float* eval = (const float*)d_in[3];
  const float* W0   = (const float*)d_in[4];
  const float* b0   = (const float*)d_in[5];
  const float* W1   = (const float*)d_in[6];
  const float* b1   = (const float*)d_in[7];
  const float* W2   = (const float*)d_in[8];
  const float* b2   = (const float*)d_in[9];
  float* out = (float*)d_out;

  char* ws = (char*)d_ws;
  float* bufA = (float*)ws;                        // s0/s1/s2  (<= 102.4 MB)
  float* bufB = (float*)(ws + 102400000);          // h1/h2     (<= 102.4 MB)

  const int M = N_NODES;
  dim3 blk(256);

  // Layer 0: s0 = x @ W0 + b0    [100000 x 256]
  gemm_kernel<false><<<dim3(1563, 4), blk, 0, stream>>>(x, W0, b0, bufA, M, 512, 256);
  // h1 = relu(spmm(s0))  (relu fused into next gemm's X load)
  hipMemsetAsync(bufB, 0, (size_t)M * 256 * 4, stream);
  spmm_kernel<256, 6, 64><<<800000, blk, 0, stream>>>(esrc, edst, eval, bufA, bufB);

  // Layer 1: s1 = relu(h1) @ W1 + b1   [100000 x 128]
  gemm_kernel<true><<<dim3(1563, 2), blk, 0, stream>>>(bufB, W1, b1, bufA, M, 256, 128);
  hipMemsetAsync(bufB, 0, (size_t)M * 128 * 4, stream);
  spmm_kernel<128, 5, 32><<<400000, blk, 0, stream>>>(esrc, edst, eval, bufA, bufB);

  // Layer 2: s2 = relu(h2) @ W2 + b2   [100000 x 40]
  gemm_kernel<true><<<dim3(1563, 1), blk, 0, stream>>>(bufB, W2, b2, bufA, M, 128, 40);
  hipMemsetAsync(out, 0, (size_t)M * 40 * 4, stream);
  spmm_kernel<40, 4, 10><<<200000, blk, 0, stream>>>(esrc, edst, eval, bufA, out);

  // log_softmax in-place on d_out
  logsoftmax_kernel<<<25000, blk, 0, stream>>>(out, M);
}

// Round 2
// 1755.976 us; speedup vs baseline: 10.5887x; 10.5887x over previous
//
#include <hip/hip_runtime.h>
#include <hip/hip_bf16.h>
#include <math.h>

#define N_NODES 100000
#define N_EDGES 3200000

typedef __hip_bfloat16 bf16_t;

// ---------- bf16 helpers (manual, branch-free) ----------
__device__ inline float2 bf2_to_f2(unsigned u) {
  float2 f;
  f.x = __uint_as_float(u << 16);
  f.y = __uint_as_float(u & 0xffff0000u);
  return f;
}
__device__ inline unsigned f2_to_bf2(float x, float y) {
  unsigned ux = __float_as_uint(x);
  unsigned uy = __float_as_uint(y);
  unsigned bx = (ux + 0x7fffu + ((ux >> 16) & 1u)) >> 16;
  unsigned by = (uy + 0x7fffu + ((uy >> 16) & 1u)) & 0xffff0000u;
  return bx | by;
}

// ---------------------------------------------------------------------------
// CSR build: histogram -> block scan -> scan of block sums -> finalize -> scatter
// ---------------------------------------------------------------------------
__global__ __launch_bounds__(256) void hist_kernel(const int* __restrict__ edst,
                                                   int* __restrict__ deg) {
  int e = blockIdx.x * 256 + threadIdx.x;
  if (e < N_EDGES) atomicAdd(&deg[edst[e]], 1);
}

__global__ __launch_bounds__(1024) void scan1_kernel(const int* __restrict__ deg,
                                                     int* __restrict__ scanned,
                                                     int* __restrict__ bsum, int n) {
  __shared__ int tmp[1024];
  int gid = blockIdx.x * 1024 + threadIdx.x;
  int v = (gid < n) ? deg[gid] : 0;
  tmp[threadIdx.x] = v;
  __syncthreads();
  #pragma unroll
  for (int off = 1; off < 1024; off <<= 1) {
    int t = (threadIdx.x >= off) ? tmp[threadIdx.x - off] : 0;
    __syncthreads();
    tmp[threadIdx.x] += t;
    __syncthreads();
  }
  if (gid < n) scanned[gid] = tmp[threadIdx.x] - v;  // exclusive within block
  if (threadIdx.x == 1023) bsum[blockIdx.x] = tmp[1023];
}

__global__ void scan2_kernel(int* __restrict__ bsum, int nb) {
  if (blockIdx.x == 0 && threadIdx.x == 0) {
    int run = 0;
    for (int i = 0; i < nb; ++i) { int t = bsum[i]; bsum[i] = run; run += t; }
  }
}

__global__ __launch_bounds__(1024) void finalize_kernel(
    const int* __restrict__ scanned, const int* __restrict__ bsum,
    int* __restrict__ rowptr, int* __restrict__ cursor, int n) {
  int gid = blockIdx.x * 1024 + threadIdx.x;
  if (gid < n) {
    int v = scanned[gid] + bsum[gid >> 10];
    rowptr[gid] = v;
    cursor[gid] = v;
  }
  if (gid == 0) rowptr[n] = N_EDGES;
}

__global__ __launch_bounds__(256) void scatter_kernel(
    const int* __restrict__ esrc, const int* __restrict__ edst,
    const float* __restrict__ eval, int* __restrict__ cursor,
    int2* __restrict__ csr) {
  int e = blockIdx.x * 256 + threadIdx.x;
  if (e < N_EDGES) {
    int p = atomicAdd(&cursor[edst[e]], 1);
    csr[p] = make_int2(esrc[e], __float_as_int(eval[e]));
  }
}

// ---------------------------------------------------------------------------
// Node-parallel SpMM, no atomics. Wave per node (D=256/128), half-wave (D=40).
// 2-stage pipeline: prefetch next edge + next gathered row while FMA-ing cur.
// ---------------------------------------------------------------------------
__global__ __launch_bounds__(256) void spmm256_kernel(
    const int* __restrict__ rowptr, const int2* __restrict__ csr,
    const bf16_t* __restrict__ s, bf16_t* __restrict__ h) {
  int node = blockIdx.x * 4 + (threadIdx.x >> 6);
  int lane = threadIdx.x & 63;
  if (node >= N_NODES) return;
  int beg = rowptr[node], end = rowptr[node + 1];
  float4 acc = make_float4(0.f, 0.f, 0.f, 0.f);
  if (beg < end) {
    int2 ec = csr[beg];
    uint2 rc = *((const uint2*)(s + (size_t)ec.x * 256) + lane);
    for (int i = beg + 1; i < end; ++i) {
      int2 en = csr[i];
      uint2 rn = *((const uint2*)(s + (size_t)en.x * 256) + lane);
      float val = __int_as_float(ec.y);
      float2 f0 = bf2_to_f2(rc.x), f1 = bf2_to_f2(rc.y);
      acc.x += val * f0.x; acc.y += val * f0.y;
      acc.z += val * f1.x; acc.w += val * f1.y;
      ec = en; rc = rn;
    }
    float val = __int_as_float(ec.y);
    float2 f0 = bf2_to_f2(rc.x), f1 = bf2_to_f2(rc.y);
    acc.x += val * f0.x; acc.y += val * f0.y;
    acc.z += val * f1.x; acc.w += val * f1.y;
  }
  uint2 o = make_uint2(f2_to_bf2(acc.x, acc.y), f2_to_bf2(acc.z, acc.w));
  *((uint2*)(h + (size_t)node * 256) + lane) = o;
}

__global__ __launch_bounds__(256) void spmm128_kernel(
    const int* __restrict__ rowptr, const int2* __restrict__ csr,
    const bf16_t* __restrict__ s, bf16_t* __restrict__ h) {
  int node = blockIdx.x * 4 + (threadIdx.x >> 6);
  int lane = threadIdx.x & 63;
  if (node >= N_NODES) return;
  int beg = rowptr[node], end = rowptr[node + 1];
  float2 acc = make_float2(0.f, 0.f);
  if (beg < end) {
    int2 ec = csr[beg];
    unsigned rc = *((const unsigned*)(s + (size_t)ec.x * 128) + lane);
    for (int i = beg + 1; i < end; ++i) {
      int2 en = csr[i];
      unsigned rn = *((const unsigned*)(s + (size_t)en.x * 128) + lane);
      float val = __int_as_float(ec.y);
      float2 f = bf2_to_f2(rc);
      acc.x += val * f.x; acc.y += val * f.y;
      ec = en; rc = rn;
    }
    float val = __int_as_float(ec.y);
    float2 f = bf2_to_f2(rc);
    acc.x += val * f.x; acc.y += val * f.y;
  }
  *((unsigned*)(h + (size_t)node * 128) + lane) = f2_to_bf2(acc.x, acc.y);
}

// D=40, fp32 output (final logits). Half-wave (32 lanes) per node, 20 active.
__global__ __launch_bounds__(256) void spmm40_kernel(
    const int* __restrict__ rowptr, const int2* __restrict__ csr,
    const bf16_t* __restrict__ s, float* __restrict__ out) {
  int node = blockIdx.x * 8 + (threadIdx.x >> 5);
  int l = threadIdx.x & 31;
  if (node >= N_NODES) return;
  bool active = (l < 20);
  int beg = rowptr[node], end = rowptr[node + 1];
  float2 acc = make_float2(0.f, 0.f);
  if (beg < end) {
    int2 ec = csr[beg];
    unsigned rc = active ? *((const unsigned*)(s + (size_t)ec.x * 40) + l) : 0u;
    for (int i = beg + 1; i < end; ++i) {
      int2 en = csr[i];
      unsigned rn = active ? *((const unsigned*)(s + (size_t)en.x * 40) + l) : 0u;
      float val = __int_as_float(ec.y);
      float2 f = bf2_to_f2(rc);
      acc.x += val * f.x; acc.y += val * f.y;
      ec = en; rc = rn;
    }
    float val = __int_as_float(ec.y);
    float2 f = bf2_to_f2(rc);
    acc.x += val * f.x; acc.y += val * f.y;
  }
  if (active) *((float2*)(out + (size_t)node * 40) + l) = acc;
}

// ---------------------------------------------------------------------------
// Tiled GEMM: out_bf16[M x N] = act(X)[M x K] @ W_f32[K x N] + bias.
// TIN = float or bf16; RELU applied to X on load. fp32 accumulate.
// ---------------------------------------------------------------------------
template<typename TIN, bool RELU>
__global__ __launch_bounds__(256) void gemm_kernel(
    const TIN* __restrict__ X, const float* __restrict__ W,
    const float* __restrict__ bias, bf16_t* __restrict__ out,
    int M, int K, int N) {
  constexpr int BM = 64, BN = 64, BK = 16;
  __shared__ float xs[BK][BM + 4];
  __shared__ float ws[BK][BN];

  const int tid = threadIdx.x;
  const int bm = blockIdx.x * BM;
  const int bn = blockIdx.y * BN;
  const int tx = tid & 15;
  const int ty = tid >> 4;
  const int lr = tid >> 2;
  const int lq = tid & 3;
  const int wk = tid >> 4;
  const int wq = tid & 15;

  float acc[4][4] = {{0.f}};

  for (int k0 = 0; k0 < K; k0 += BK) {
    {
      int row = bm + lr;
      float4 v = make_float4(0.f, 0.f, 0.f, 0.f);
      if (row < M) {
        if constexpr (sizeof(TIN) == 4) {
          v = *(const float4*)((const float*)X + (size_t)row * K + k0 + lq * 4);
        } else {
          uint2 u = *(const uint2*)((const bf16_t*)X + (size_t)row * K + k0 + lq * 4);
          float2 f0 = bf2_to_f2(u.x), f1 = bf2_to_f2(u.y);
          v = make_float4(f0.x, f0.y, f1.x, f1.y);
        }
      }
      if (RELU) {
        v.x = fmaxf(v.x, 0.f); v.y = fmaxf(v.y, 0.f);
        v.z = fmaxf(v.z, 0.f); v.w = fmaxf(v.w, 0.f);
      }
      xs[lq * 4 + 0][lr] = v.x;
      xs[lq * 4 + 1][lr] = v.y;
      xs[lq * 4 + 2][lr] = v.z;
      xs[lq * 4 + 3][lr] = v.w;
    }
    {
      int col = bn + wq * 4;
      float4 v = make_float4(0.f, 0.f, 0.f, 0.f);
      if (col < N) v = *(const float4*)(W + (size_t)(k0 + wk) * N + col);
      *(float4*)&ws[wk][wq * 4] = v;
    }
    __syncthreads();

    #pragma unroll
    for (int kk = 0; kk < BK; ++kk) {
      float4 xv = *(const float4*)&xs[kk][ty * 4];
      float4 wv = *(const float4*)&ws[kk][tx * 4];
      acc[0][0] += xv.x * wv.x; acc[0][1] += xv.x * wv.y;
      acc[0][2] += xv.x * wv.z; acc[0][3] += xv.x * wv.w;
      acc[1][0] += xv.y * wv.x; acc[1][1] += xv.y * wv.y;
      acc[1][2] += xv.y * wv.z; acc[1][3] += xv.y * wv.w;
      acc[2][0] += xv.z * wv.x; acc[2][1] += xv.z * wv.y;
      acc[2][2] += xv.z * wv.z; acc[2][3] += xv.z * wv.w;
      acc[3][0] += xv.w * wv.x; acc[3][1] += xv.w * wv.y;
      acc[3][2] += xv.w * wv.z; acc[3][3] += xv.w * wv.w;
    }
    __syncthreads();
  }

  const int col0 = bn + tx * 4;
  if (col0 < N) {
    #pragma unroll
    for (int i = 0; i < 4; ++i) {
      int row = bm + ty * 4 + i;
      if (row < M) {
        float o0 = acc[i][0] + bias[col0 + 0];
        float o1 = acc[i][1] + bias[col0 + 1];
        float o2 = acc[i][2] + bias[col0 + 2];
        float o3 = acc[i][3] + bias[col0 + 3];
        uint2 o = make_uint2(f2_to_bf2(o0, o1), f2_to_bf2(o2, o3));
        *(uint2*)(out + (size_t)row * N + col0) = o;
      }
    }
  }
}

// ---------------------------------------------------------------------------
// log_softmax over 40 classes; one wave per row, in-place fp32.
// ---------------------------------------------------------------------------
__global__ __launch_bounds__(256) void logsoftmax_kernel(float* __restrict__ io,
                                                         int M) {
  const int lane = threadIdx.x & 63;
  const int row = blockIdx.x * 4 + (threadIdx.x >> 6);
  if (row >= M) return;
  float v = (lane < 40) ? io[(size_t)row * 40 + lane] : -INFINITY;
  float m = v;
  #pragma unroll
  for (int off = 32; off > 0; off >>= 1)
    m = fmaxf(m, __shfl_xor(m, off));
  float ex = (lane < 40) ? __expf(v - m) : 0.f;
  float sum = ex;
  #pragma unroll
  for (int off = 32; off > 0; off >>= 1)
    sum += __shfl_xor(sum, off);
  if (lane < 40) io[(size_t)row * 40 + lane] = v - m - logf(sum);
}

// ---------------------------------------------------------------------------
extern "C" void kernel_launch(void* const* d_in, const int* in_sizes, int n_in,
                              void* d_out, int out_size, void* d_ws,
                              size_t ws_size, hipStream_t stream) {
  const float* x    = (const float*)d_in[0];
  const int*   esrc = (const int*)d_in[1];
  const int*   edst = (const int*)d_in[2];
  const float* eval = (const float*)d_in[3];
  const float* W0   = (const float*)d_in[4];
  const float* b0   = (const float*)d_in[5];
  const float* W1   = (const float*)d_in[6];
  const float* b1   = (const float*)d_in[7];
  const float* W2   = (const float*)d_in[8];
  const float* b2   = (const float*)d_in[9];
  float* out = (float*)d_out;

  char* ws = (char*)d_ws;
  // layout (bytes):
  bf16_t* bufA   = (bf16_t*)(ws + 0);            // s buffers, <= 51.2 MB
  bf16_t* bufB   = (bf16_t*)(ws + 51200000);     // h buffers, <= 51.2 MB
  int2*   csr    = (int2*)  (ws + 102400000);    // 25.6 MB
  int*    rowptr = (int*)   (ws + 128000000);    // 400,004 B
  int*    cursor = (int*)   (ws + 128400016);
  int*    deg    = (int*)   (ws + 128800016);
  int*    scanned= (int*)   (ws + 129200016);
  int*    bsum   = (int*)   (ws + 129600016);

  const int M = N_NODES;
  dim3 blk(256);

  // ---- CSR build (by destination) ----
  hipMemsetAsync(deg, 0, (size_t)N_NODES * 4, stream);
  hist_kernel<<<(N_EDGES + 255) / 256, blk, 0, stream>>>(edst, deg);
  const int nScanBlk = (N_NODES + 1023) / 1024;  // 98
  scan1_kernel<<<nScanBlk, 1024, 0, stream>>>(deg, scanned, bsum, N_NODES);
  scan2_kernel<<<1, 64, 0, stream>>>(bsum, nScanBlk);
  finalize_kernel<<<nScanBlk, 1024, 0, stream>>>(scanned, bsum, rowptr, cursor, N_NODES);
  scatter_kernel<<<(N_EDGES + 255) / 256, blk, 0, stream>>>(esrc, edst, eval, cursor, csr);

  // ---- Layer 0: s0 = x @ W0 + b0  [100000 x 256] bf16 ----
  gemm_kernel<float, false><<<dim3(1563, 4), blk, 0, stream>>>(x, W0, b0, bufA, M, 512, 256);
  spmm256_kernel<<<25000, blk, 0, stream>>>(rowptr, csr, bufA, bufB);

  // ---- Layer 1: s1 = relu(h1) @ W1 + b1  [100000 x 128] bf16 ----
  gemm_kernel<bf16_t, true><<<dim3(1563, 2), blk, 0, stream>>>(bufB, W1, b1, bufA, M, 256, 128);
  spmm128_kernel<<<25000, blk, 0, stream>>>(rowptr, csr, bufA, bufB);

  // ---- Layer 2: s2 = relu(h2) @ W2 + b2  [100000 x 40] bf16 ----
  gemm_kernel<bf16_t, true><<<dim3(1563, 1), blk, 0, stream>>>(bufB, W2, b2, bufA, M, 128, 40);
  spmm40_kernel<<<12500, blk, 0, stream>>>(rowptr, csr, bufA, out);

  // ---- log_softmax in-place on d_out ----
  logsoftmax_kernel<<<25000, blk, 0, stream>>>(out, M);
}

// Round 3
// 1453.961 us; speedup vs baseline: 12.7881x; 1.2077x over previous
//
#include <hip/hip_runtime.h>
#include <hip/hip_bf16.h>
#include <math.h>

#define N_NODES 100000
#define N_EDGES 3200000

typedef __hip_bfloat16 bf16_t;
typedef __attribute__((ext_vector_type(8))) short bf16x8;
typedef __attribute__((ext_vector_type(4))) float floatx4;

// ---------- bf16 helpers (manual, branch-free) ----------
__device__ inline float2 bf2_to_f2(unsigned u) {
  float2 f;
  f.x = __uint_as_float(u << 16);
  f.y = __uint_as_float(u & 0xffff0000u);
  return f;
}
__device__ inline unsigned f2_to_bf2(float x, float y) {
  unsigned ux = __float_as_uint(x);
  unsigned uy = __float_as_uint(y);
  unsigned bx = (ux + 0x7fffu + ((ux >> 16) & 1u)) >> 16;
  unsigned by = (uy + 0x7fffu + ((uy >> 16) & 1u)) & 0xffff0000u;
  return bx | by;
}
__device__ inline unsigned f_to_bf1(float x) {
  unsigned u = __float_as_uint(x);
  return (u + 0x7fffu + ((u >> 16) & 1u)) >> 16;
}
// relu on a packed pair of bf16
__device__ inline unsigned relu_bf2(unsigned u) {
  unsigned lo = (u & 0x8000u) ? 0u : (u & 0xFFFFu);
  unsigned hi = (u & 0x80000000u) ? 0u : (u & 0xFFFF0000u);
  return lo | hi;
}

// ---------------------------------------------------------------------------
// CSR build: histogram -> block scan -> scan of block sums -> finalize -> scatter
// ---------------------------------------------------------------------------
__global__ __launch_bounds__(256) void hist_kernel(const int* __restrict__ edst,
                                                   int* __restrict__ deg) {
  int e = blockIdx.x * 256 + threadIdx.x;
  if (e < N_EDGES) atomicAdd(&deg[edst[e]], 1);
}

__global__ __launch_bounds__(1024) void scan1_kernel(const int* __restrict__ deg,
                                                     int* __restrict__ scanned,
                                                     int* __restrict__ bsum, int n) {
  __shared__ int tmp[1024];
  int gid = blockIdx.x * 1024 + threadIdx.x;
  int v = (gid < n) ? deg[gid] : 0;
  tmp[threadIdx.x] = v;
  __syncthreads();
  #pragma unroll
  for (int off = 1; off < 1024; off <<= 1) {
    int t = (threadIdx.x >= off) ? tmp[threadIdx.x - off] : 0;
    __syncthreads();
    tmp[threadIdx.x] += t;
    __syncthreads();
  }
  if (gid < n) scanned[gid] = tmp[threadIdx.x] - v;  // exclusive within block
  if (threadIdx.x == 1023) bsum[blockIdx.x] = tmp[1023];
}

__global__ void scan2_kernel(int* __restrict__ bsum, int nb) {
  if (blockIdx.x == 0 && threadIdx.x == 0) {
    int run = 0;
    for (int i = 0; i < nb; ++i) { int t = bsum[i]; bsum[i] = run; run += t; }
  }
}

__global__ __launch_bounds__(1024) void finalize_kernel(
    const int* __restrict__ scanned, const int* __restrict__ bsum,
    int* __restrict__ rowptr, int* __restrict__ cursor, int n) {
  int gid = blockIdx.x * 1024 + threadIdx.x;
  if (gid < n) {
    int v = scanned[gid] + bsum[gid >> 10];
    rowptr[gid] = v;
    cursor[gid] = v;
  }
  if (gid == 0) rowptr[n] = N_EDGES;
}

__global__ __launch_bounds__(256) void scatter_kernel(
    const int* __restrict__ esrc, const int* __restrict__ edst,
    const float* __restrict__ eval, int* __restrict__ cursor,
    int2* __restrict__ csr) {
  int e = blockIdx.x * 256 + threadIdx.x;
  if (e < N_EDGES) {
    int p = atomicAdd(&cursor[edst[e]], 1);
    csr[p] = make_int2(esrc[e], __float_as_int(eval[e]));
  }
}

// ---------------------------------------------------------------------------
// W transpose + fp32->bf16: Wt[n*K + k] = bf16(W[k*N + n]). K = 1<<ksh.
// ---------------------------------------------------------------------------
__global__ __launch_bounds__(256) void transpose_w_kernel(
    const float* __restrict__ W, unsigned short* __restrict__ Wt,
    int ksh, int N) {
  int idx = blockIdx.x * 256 + threadIdx.x;
  int K = 1 << ksh;
  if (idx >= N * K) return;
  int n = idx >> ksh;
  int k = idx & (K - 1);
  Wt[idx] = (unsigned short)f_to_bf1(W[(size_t)k * N + n]);
}

// ---------------------------------------------------------------------------
// MFMA bf16 GEMM: out_bf16[M x N] = act(X)[M x K] @ W[K x N] + bias
// Wt is W^T in bf16 (n-major, k-contiguous). BM=BN=128, BK=32.
// 4 waves in 2x2; each wave computes 64x64 via 4x4 tiles of 16x16x32 MFMA.
// AFP32: X is fp32 (layer 0); else bf16. RELU applied to X on staging.
// ---------------------------------------------------------------------------
template<bool AFP32, bool RELU>
__global__ __launch_bounds__(256) void mfma_gemm_kernel(
    const void* __restrict__ Xv, const unsigned short* __restrict__ Wt,
    const float* __restrict__ bias, bf16_t* __restrict__ out,
    int M, int K, int N) {
  constexpr int BM = 128, BN = 128, BK = 32, LDSTR = 40;  // stride 40 bf16 = 80B
  __shared__ __align__(16) unsigned short a_lds[BM * LDSTR];
  __shared__ __align__(16) unsigned short b_lds[BN * LDSTR];

  const int tid = threadIdx.x;
  const int lane = tid & 63;
  const int wave = tid >> 6;
  const int q = lane >> 4;       // quad 0..3
  const int r16 = lane & 15;
  const int wm = (wave >> 1) * 64;
  const int wn = (wave & 1) * 64;
  const int bm = blockIdx.x * BM;
  const int bn = blockIdx.y * BN;

  floatx4 acc[4][4] = {};

  for (int k0 = 0; k0 < K; k0 += BK) {
    // ---- stage A (128 x 32) ----
    if (AFP32) {
      const float* X = (const float*)Xv;
      #pragma unroll
      for (int i = 0; i < 4; ++i) {
        int c = tid + i * 256;           // 1024 chunks of 4 floats
        int row = c >> 3, kc = (c & 7) * 4;
        float4 v = make_float4(0.f, 0.f, 0.f, 0.f);
        if (bm + row < M)
          v = *(const float4*)(X + (size_t)(bm + row) * K + k0 + kc);
        unsigned lo = f2_to_bf2(v.x, v.y);
        unsigned hi = f2_to_bf2(v.z, v.w);
        *(uint2*)&a_lds[row * LDSTR + kc] = make_uint2(lo, hi);
      }
    } else {
      const unsigned short* X = (const unsigned short*)Xv;
      #pragma unroll
      for (int i = 0; i < 2; ++i) {
        int c = tid + i * 256;           // 512 chunks of 8 bf16
        int row = c >> 2, kc = (c & 3) * 8;
        uint4 v = make_uint4(0u, 0u, 0u, 0u);
        if (bm + row < M)
          v = *(const uint4*)(X + (size_t)(bm + row) * K + k0 + kc);
        if (RELU) {
          v.x = relu_bf2(v.x); v.y = relu_bf2(v.y);
          v.z = relu_bf2(v.z); v.w = relu_bf2(v.w);
        }
        *(uint4*)&a_lds[row * LDSTR + kc] = v;
      }
    }
    // ---- stage B (128 x 32) from Wt rows ----
    #pragma unroll
    for (int i = 0; i < 2; ++i) {
      int c = tid + i * 256;
      int row = c >> 2, kc = (c & 3) * 8;
      uint4 v = make_uint4(0u, 0u, 0u, 0u);
      if (bn + row < N)
        v = *(const uint4*)(Wt + (size_t)(bn + row) * K + k0 + kc);
      *(uint4*)&b_lds[row * LDSTR + kc] = v;
    }
    __syncthreads();

    // ---- fragments + MFMA ----
    bf16x8 af[4], bfr[4];
    #pragma unroll
    for (int t = 0; t < 4; ++t)
      af[t] = *(const bf16x8*)&a_lds[(wm + t * 16 + r16) * LDSTR + q * 8];
    #pragma unroll
    for (int t = 0; t < 4; ++t)
      bfr[t] = *(const bf16x8*)&b_lds[(wn + t * 16 + r16) * LDSTR + q * 8];
    #pragma unroll
    for (int mi = 0; mi < 4; ++mi)
      #pragma unroll
      for (int ni = 0; ni < 4; ++ni)
        acc[mi][ni] = __builtin_amdgcn_mfma_f32_16x16x32_bf16(
            af[mi], bfr[ni], acc[mi][ni], 0, 0, 0);
    __syncthreads();
  }

  // ---- epilogue: bias, bf16 pack (pair via shfl), store uint ----
  #pragma unroll
  for (int ni = 0; ni < 4; ++ni) {
    int col = bn + wn + ni * 16 + r16;
    float bv = (col < N) ? bias[col] : 0.f;
    #pragma unroll
    for (int mi = 0; mi < 4; ++mi) {
      #pragma unroll
      for (int r = 0; r < 4; ++r) {
        int row = bm + wm + mi * 16 + q * 4 + r;
        float v = acc[mi][ni][r] + bv;
        int bits = (int)f_to_bf1(v);
        int other = __shfl_xor(bits, 1);
        if (((lane & 1) == 0) && row < M && col < N) {
          *(unsigned*)((unsigned short*)out + (size_t)row * N + col) =
              (unsigned)bits | ((unsigned)other << 16);
        }
      }
    }
  }
}

// ---------------------------------------------------------------------------
// Node-parallel SpMM, no atomics. Wave per node (D=256/128), half-wave (D=40).
// ---------------------------------------------------------------------------
__global__ __launch_bounds__(256) void spmm256_kernel(
    const int* __restrict__ rowptr, const int2* __restrict__ csr,
    const bf16_t* __restrict__ s, bf16_t* __restrict__ h) {
  int node = blockIdx.x * 4 + (threadIdx.x >> 6);
  int lane = threadIdx.x & 63;
  if (node >= N_NODES) return;
  int beg = rowptr[node], end = rowptr[node + 1];
  float4 acc = make_float4(0.f, 0.f, 0.f, 0.f);
  if (beg < end) {
    int2 ec = csr[beg];
    uint2 rc = *((const uint2*)(s + (size_t)ec.x * 256) + lane);
    for (int i = beg + 1; i < end; ++i) {
      int2 en = csr[i];
      uint2 rn = *((const uint2*)(s + (size_t)en.x * 256) + lane);
      float val = __int_as_float(ec.y);
      float2 f0 = bf2_to_f2(rc.x), f1 = bf2_to_f2(rc.y);
      acc.x += val * f0.x; acc.y += val * f0.y;
      acc.z += val * f1.x; acc.w += val * f1.y;
      ec = en; rc = rn;
    }
    float val = __int_as_float(ec.y);
    float2 f0 = bf2_to_f2(rc.x), f1 = bf2_to_f2(rc.y);
    acc.x += val * f0.x; acc.y += val * f0.y;
    acc.z += val * f1.x; acc.w += val * f1.y;
  }
  uint2 o = make_uint2(f2_to_bf2(acc.x, acc.y), f2_to_bf2(acc.z, acc.w));
  *((uint2*)(h + (size_t)node * 256) + lane) = o;
}

__global__ __launch_bounds__(256) void spmm128_kernel(
    const int* __restrict__ rowptr, const int2* __restrict__ csr,
    const bf16_t* __restrict__ s, bf16_t* __restrict__ h) {
  int node = blockIdx.x * 4 + (threadIdx.x >> 6);
  int lane = threadIdx.x & 63;
  if (node >= N_NODES) return;
  int beg = rowptr[node], end = rowptr[node + 1];
  float2 acc = make_float2(0.f, 0.f);
  if (beg < end) {
    int2 ec = csr[beg];
    unsigned rc = *((const unsigned*)(s + (size_t)ec.x * 128) + lane);
    for (int i = beg + 1; i < end; ++i) {
      int2 en = csr[i];
      unsigned rn = *((const unsigned*)(s + (size_t)en.x * 128) + lane);
      float val = __int_as_float(ec.y);
      float2 f = bf2_to_f2(rc);
      acc.x += val * f.x; acc.y += val * f.y;
      ec = en; rc = rn;
    }
    float val = __int_as_float(ec.y);
    float2 f = bf2_to_f2(rc);
    acc.x += val * f.x; acc.y += val * f.y;
  }
  *((unsigned*)(h + (size_t)node * 128) + lane) = f2_to_bf2(acc.x, acc.y);
}

// D=40, fp32 output (final logits). Half-wave (32 lanes) per node, 20 active.
__global__ __launch_bounds__(256) void spmm40_kernel(
    const int* __restrict__ rowptr, const int2* __restrict__ csr,
    const bf16_t* __restrict__ s, float* __restrict__ out) {
  int node = blockIdx.x * 8 + (threadIdx.x >> 5);
  int l = threadIdx.x & 31;
  if (node >= N_NODES) return;
  bool active = (l < 20);
  int beg = rowptr[node], end = rowptr[node + 1];
  float2 acc = make_float2(0.f, 0.f);
  if (beg < end) {
    int2 ec = csr[beg];
    unsigned rc = active ? *((const unsigned*)(s + (size_t)ec.x * 40) + l) : 0u;
    for (int i = beg + 1; i < end; ++i) {
      int2 en = csr[i];
      unsigned rn = active ? *((const unsigned*)(s + (size_t)en.x * 40) + l) : 0u;
      float val = __int_as_float(ec.y);
      float2 f = bf2_to_f2(rc);
      acc.x += val * f.x; acc.y += val * f.y;
      ec = en; rc = rn;
    }
    float val = __int_as_float(ec.y);
    float2 f = bf2_to_f2(rc);
    acc.x += val * f.x; acc.y += val * f.y;
  }
  if (active) *((float2*)(out + (size_t)node * 40) + l) = acc;
}

// ---------------------------------------------------------------------------
// log_softmax over 40 classes; one wave per row, in-place fp32.
// ---------------------------------------------------------------------------
__global__ __launch_bounds__(256) void logsoftmax_kernel(float* __restrict__ io,
                                                         int M) {
  const int lane = threadIdx.x & 63;
  const int row = blockIdx.x * 4 + (threadIdx.x >> 6);
  if (row >= M) return;
  float v = (lane < 40) ? io[(size_t)row * 40 + lane] : -INFINITY;
  float m = v;
  #pragma unroll
  for (int off = 32; off > 0; off >>= 1)
    m = fmaxf(m, __shfl_xor(m, off));
  float ex = (lane < 40) ? __expf(v - m) : 0.f;
  float sum = ex;
  #pragma unroll
  for (int off = 32; off > 0; off >>= 1)
    sum += __shfl_xor(sum, off);
  if (lane < 40) io[(size_t)row * 40 + lane] = v - m - logf(sum);
}

// ---------------------------------------------------------------------------
extern "C" void kernel_launch(void* const* d_in, const int* in_sizes, int n_in,
                              void* d_out, int out_size, void* d_ws,
                              size_t ws_size, hipStream_t stream) {
  const float* x    = (const float*)d_in[0];
  const int*   esrc = (const int*)d_in[1];
  const int*   edst = (const int*)d_in[2];
  const float* eval = (const float*)d_in[3];
  const float* W0   = (const float*)d_in[4];
  const float* b0   = (const float*)d_in[5];
  const float* W1   = (const float*)d_in[6];
  const float* b1   = (const float*)d_in[7];
  const float* W2   = (const float*)d_in[8];
  const float* b2   = (const float*)d_in[9];
  float* out = (float*)d_out;

  char* ws = (char*)d_ws;
  bf16_t* bufA   = (bf16_t*)(ws + 0);            // s buffers, <= 51.2 MB
  bf16_t* bufB   = (bf16_t*)(ws + 51200000);     // h buffers, <= 51.2 MB
  int2*   csr    = (int2*)  (ws + 102400000);    // 25.6 MB
  int*    rowptr = (int*)   (ws + 128000000);    // 400,004 B
  int*    cursor = (int*)   (ws + 128400016);
  int*    deg    = (int*)   (ws + 128800016);
  int*    scanned= (int*)   (ws + 129200016);
  int*    bsum   = (int*)   (ws + 129600016);
  unsigned short* Wt0 = (unsigned short*)(ws + 129700000);  // 262144 B
  unsigned short* Wt1 = (unsigned short*)(ws + 130000000);  //  65536 B
  unsigned short* Wt2 = (unsigned short*)(ws + 130100000);  //  10240 B

  const int M = N_NODES;
  dim3 blk(256);

  // ---- CSR build (by destination) ----
  hipMemsetAsync(deg, 0, (size_t)N_NODES * 4, stream);
  hist_kernel<<<(N_EDGES + 255) / 256, blk, 0, stream>>>(edst, deg);
  const int nScanBlk = (N_NODES + 1023) / 1024;  // 98
  scan1_kernel<<<nScanBlk, 1024, 0, stream>>>(deg, scanned, bsum, N_NODES);
  scan2_kernel<<<1, 64, 0, stream>>>(bsum, nScanBlk);
  finalize_kernel<<<nScanBlk, 1024, 0, stream>>>(scanned, bsum, rowptr, cursor, N_NODES);
  scatter_kernel<<<(N_EDGES + 255) / 256, blk, 0, stream>>>(esrc, edst, eval, cursor, csr);

  // ---- W transposes (fp32 -> bf16, n-major) ----
  transpose_w_kernel<<<(512 * 256 + 255) / 256, blk, 0, stream>>>(W0, Wt0, 9, 256);
  transpose_w_kernel<<<(256 * 128 + 255) / 256, blk, 0, stream>>>(W1, Wt1, 8, 128);
  transpose_w_kernel<<<(128 * 40 + 255) / 256, blk, 0, stream>>>(W2, Wt2, 7, 40);

  const int MB = (M + 127) / 128;  // 782

  // ---- Layer 0: s0 = x @ W0 + b0  [100000 x 256] bf16 ----
  mfma_gemm_kernel<true, false><<<dim3(MB, 2), blk, 0, stream>>>(
      x, Wt0, b0, bufA, M, 512, 256);
  spmm256_kernel<<<25000, blk, 0, stream>>>(rowptr, csr, bufA, bufB);

  // ---- Layer 1: s1 = relu(h1) @ W1 + b1  [100000 x 128] bf16 ----
  mfma_gemm_kernel<false, true><<<dim3(MB, 1), blk, 0, stream>>>(
      bufB, Wt1, b1, bufA, M, 256, 128);
  spmm128_kernel<<<25000, blk, 0, stream>>>(rowptr, csr, bufA, bufB);

  // ---- Layer 2: s2 = relu(h2) @ W2 + b2  [100000 x 40] bf16 ----
  mfma_gemm_kernel<false, true><<<dim3(MB, 1), blk, 0, stream>>>(
      bufB, Wt2, b2, bufA, M, 128, 40);
  spmm40_kernel<<<12500, blk, 0, stream>>>(rowptr, csr, bufA, out);

  // ---- log_softmax in-place on d_out ----
  logsoftmax_kernel<<<25000, blk, 0, stream>>>(out, M);
}

// Round 4
// 1308.779 us; speedup vs baseline: 14.2067x; 1.1109x over previous
//
#include <hip/hip_runtime.h>
#include <hip/hip_bf16.h>
#include <math.h>

#define N_NODES 100000
#define N_EDGES 3200000
#define NBUK 782      // ceil(100000 / 128), bucket = dst >> 7
#define BCAP 4800     // per-bucket LDS capacity (mean 4096, sigma ~64)

typedef __hip_bfloat16 bf16_t;
typedef __attribute__((ext_vector_type(8))) short bf16x8;
typedef __attribute__((ext_vector_type(4))) float floatx4;

// ---------- bf16 helpers (manual, branch-free) ----------
__device__ inline float2 bf2_to_f2(unsigned u) {
  float2 f;
  f.x = __uint_as_float(u << 16);
  f.y = __uint_as_float(u & 0xffff0000u);
  return f;
}
__device__ inline unsigned f2_to_bf2(float x, float y) {
  unsigned ux = __float_as_uint(x);
  unsigned uy = __float_as_uint(y);
  unsigned bx = (ux + 0x7fffu + ((ux >> 16) & 1u)) >> 16;
  unsigned by = (uy + 0x7fffu + ((uy >> 16) & 1u)) & 0xffff0000u;
  return bx | by;
}
__device__ inline unsigned f_to_bf1(float x) {
  unsigned u = __float_as_uint(x);
  return (u + 0x7fffu + ((u >> 16) & 1u)) >> 16;
}
__device__ inline unsigned relu_bf2(unsigned u) {
  unsigned lo = (u & 0x8000u) ? 0u : (u & 0xFFFFu);
  unsigned hi = (u & 0x80000000u) ? 0u : (u & 0xFFFF0000u);
  return lo | hi;
}

// ---------------------------------------------------------------------------
// CSR build, bucketed two-pass.
// cntp / cursorp are line-padded (stride 16 ints = 64 B per counter).
// ---------------------------------------------------------------------------
__global__ __launch_bounds__(256) void bucket_hist_kernel(
    const int* __restrict__ edst, int* __restrict__ cntp) {
  __shared__ int h[NBUK];
  for (int i = threadIdx.x; i < NBUK; i += 256) h[i] = 0;
  __syncthreads();
  int start = blockIdx.x * 4096;
  int end = start + 4096 < N_EDGES ? start + 4096 : N_EDGES;
  for (int i = start + threadIdx.x; i < end; i += 256)
    atomicAdd(&h[edst[i] >> 7], 1);
  __syncthreads();
  for (int i = threadIdx.x; i < NBUK; i += 256)
    if (h[i]) atomicAdd(&cntp[i << 4], h[i]);
}

__global__ __launch_bounds__(1024) void scan_buckets_kernel(
    const int* __restrict__ cntp, int* __restrict__ base,
    int* __restrict__ cursorp, int* __restrict__ rowptr) {
  __shared__ int sc[1024];
  int t = threadIdx.x;
  int v = (t < NBUK) ? cntp[t << 4] : 0;
  sc[t] = v;
  __syncthreads();
  #pragma unroll
  for (int off = 1; off < 1024; off <<= 1) {
    int u = (t >= off) ? sc[t - off] : 0;
    __syncthreads();
    sc[t] += u;
    __syncthreads();
  }
  int ex = sc[t] - v;  // exclusive
  if (t < NBUK) { base[t] = ex; cursorp[t << 4] = ex; }
  if (t == NBUK - 1) base[NBUK] = ex + v;
  if (t == 0) rowptr[N_NODES] = N_EDGES;
}

__global__ __launch_bounds__(256) void bucket_scatter_kernel(
    const int* __restrict__ esrc, const int* __restrict__ edst,
    const float* __restrict__ eval, int* __restrict__ cursorp,
    int2* __restrict__ tmp) {
  int e = blockIdx.x * 256 + threadIdx.x;
  if (e < N_EDGES) {
    int d = edst[e];
    int p = atomicAdd(&cursorp[(d >> 7) << 4], 1);
    tmp[p] = make_int2(esrc[e] | ((d & 127) << 17), __float_as_int(eval[e]));
  }
}

__global__ __launch_bounds__(256) void sort_bucket_kernel(
    const int* __restrict__ base, const int2* __restrict__ tmp,
    int2* __restrict__ csr, int* __restrict__ rowptr) {
  __shared__ int2 ebuf[BCAP];
  __shared__ int bin[128], sc[128], cur[128];
  const int b = blockIdx.x, tid = threadIdx.x;
  const int bbase = base[b], bend = base[b + 1];
  const int bcnt = bend - bbase;
  if (tid < 128) bin[tid] = 0;
  __syncthreads();
  for (int i = tid; i < bcnt; i += 256) {
    int2 e = tmp[bbase + i];
    if (i < BCAP) ebuf[i] = e;
    atomicAdd(&bin[(e.x >> 17) & 127], 1);
  }
  __syncthreads();
  if (tid < 128) sc[tid] = bin[tid];
  __syncthreads();
  #pragma unroll
  for (int off = 1; off < 128; off <<= 1) {
    int u = (tid < 128 && tid >= off) ? sc[tid - off] : 0;
    __syncthreads();
    if (tid < 128) sc[tid] += u;
    __syncthreads();
  }
  if (tid < 128) {
    int ex = sc[tid] - bin[tid];
    int node = (b << 7) + tid;
    if (node < N_NODES) rowptr[node] = bbase + ex;
    cur[tid] = ex;
  }
  __syncthreads();
  for (int i = tid; i < bcnt; i += 256) {
    int2 e = (i < BCAP) ? ebuf[i] : tmp[bbase + i];
    int d = (e.x >> 17) & 127;
    int p = atomicAdd(&cur[d], 1);
    csr[bbase + p] = make_int2(e.x & 0x1FFFF, e.y);
  }
}

// ---------------------------------------------------------------------------
// W transpose + fp32->bf16: Wt[n*K + k] = bf16(W[k*N + n]). K = 1<<ksh.
// ---------------------------------------------------------------------------
__global__ __launch_bounds__(256) void transpose_w_kernel(
    const float* __restrict__ W, unsigned short* __restrict__ Wt,
    int ksh, int N) {
  int idx = blockIdx.x * 256 + threadIdx.x;
  int K = 1 << ksh;
  if (idx >= N * K) return;
  int n = idx >> ksh;
  int k = idx & (K - 1);
  Wt[idx] = (unsigned short)f_to_bf1(W[(size_t)k * N + n]);
}

// ---------------------------------------------------------------------------
// MFMA bf16 GEMM: out_bf16[M x N] = act(X)[M x K] @ W[K x N] + bias
// Wt is W^T in bf16 (n-major, k-contiguous). BM=BN=128, BK=32.
// ---------------------------------------------------------------------------
template<bool AFP32, bool RELU>
__global__ __launch_bounds__(256) void mfma_gemm_kernel(
    const void* __restrict__ Xv, const unsigned short* __restrict__ Wt,
    const float* __restrict__ bias, bf16_t* __restrict__ out,
    int M, int K, int N) {
  constexpr int BM = 128, BN = 128, BK = 32, LDSTR = 40;
  __shared__ __align__(16) unsigned short a_lds[BM * LDSTR];
  __shared__ __align__(16) unsigned short b_lds[BN * LDSTR];

  const int tid = threadIdx.x;
  const int lane = tid & 63;
  const int wave = tid >> 6;
  const int q = lane >> 4;
  const int r16 = lane & 15;
  const int wm = (wave >> 1) * 64;
  const int wn = (wave & 1) * 64;
  const int bm = blockIdx.x * BM;
  const int bn = blockIdx.y * BN;

  floatx4 acc[4][4] = {};

  for (int k0 = 0; k0 < K; k0 += BK) {
    if (AFP32) {
      const float* X = (const float*)Xv;
      #pragma unroll
      for (int i = 0; i < 4; ++i) {
        int c = tid + i * 256;
        int row = c >> 3, kc = (c & 7) * 4;
        float4 v = make_float4(0.f, 0.f, 0.f, 0.f);
        if (bm + row < M)
          v = *(const float4*)(X + (size_t)(bm + row) * K + k0 + kc);
        unsigned lo = f2_to_bf2(v.x, v.y);
        unsigned hi = f2_to_bf2(v.z, v.w);
        *(uint2*)&a_lds[row * LDSTR + kc] = make_uint2(lo, hi);
      }
    } else {
      const unsigned short* X = (const unsigned short*)Xv;
      #pragma unroll
      for (int i = 0; i < 2; ++i) {
        int c = tid + i * 256;
        int row = c >> 2, kc = (c & 3) * 8;
        uint4 v = make_uint4(0u, 0u, 0u, 0u);
        if (bm + row < M)
          v = *(const uint4*)(X + (size_t)(bm + row) * K + k0 + kc);
        if (RELU) {
          v.x = relu_bf2(v.x); v.y = relu_bf2(v.y);
          v.z = relu_bf2(v.z); v.w = relu_bf2(v.w);
        }
        *(uint4*)&a_lds[row * LDSTR + kc] = v;
      }
    }
    #pragma unroll
    for (int i = 0; i < 2; ++i) {
      int c = tid + i * 256;
      int row = c >> 2, kc = (c & 3) * 8;
      uint4 v = make_uint4(0u, 0u, 0u, 0u);
      if (bn + row < N)
        v = *(const uint4*)(Wt + (size_t)(bn + row) * K + k0 + kc);
      *(uint4*)&b_lds[row * LDSTR + kc] = v;
    }
    __syncthreads();

    bf16x8 af[4], bfr[4];
    #pragma unroll
    for (int t = 0; t < 4; ++t)
      af[t] = *(const bf16x8*)&a_lds[(wm + t * 16 + r16) * LDSTR + q * 8];
    #pragma unroll
    for (int t = 0; t < 4; ++t)
      bfr[t] = *(const bf16x8*)&b_lds[(wn + t * 16 + r16) * LDSTR + q * 8];
    #pragma unroll
    for (int mi = 0; mi < 4; ++mi)
      #pragma unroll
      for (int ni = 0; ni < 4; ++ni)
        acc[mi][ni] = __builtin_amdgcn_mfma_f32_16x16x32_bf16(
            af[mi], bfr[ni], acc[mi][ni], 0, 0, 0);
    __syncthreads();
  }

  #pragma unroll
  for (int ni = 0; ni < 4; ++ni) {
    int col = bn + wn + ni * 16 + r16;
    float bv = (col < N) ? bias[col] : 0.f;
    #pragma unroll
    for (int mi = 0; mi < 4; ++mi) {
      #pragma unroll
      for (int r = 0; r < 4; ++r) {
        int row = bm + wm + mi * 16 + q * 4 + r;
        float v = acc[mi][ni][r] + bv;
        int bits = (int)f_to_bf1(v);
        int other = __shfl_xor(bits, 1);
        if (((lane & 1) == 0) && row < M && col < N) {
          *(unsigned*)((unsigned short*)out + (size_t)row * N + col) =
              (unsigned)bits | ((unsigned)other << 16);
        }
      }
    }
  }
}

// ---------------------------------------------------------------------------
// Node-parallel SpMM, no atomics.
// ---------------------------------------------------------------------------
__global__ __launch_bounds__(256) void spmm256_kernel(
    const int* __restrict__ rowptr, const int2* __restrict__ csr,
    const bf16_t* __restrict__ s, bf16_t* __restrict__ h) {
  int node = blockIdx.x * 4 + (threadIdx.x >> 6);
  int lane = threadIdx.x & 63;
  if (node >= N_NODES) return;
  int beg = rowptr[node], end = rowptr[node + 1];
  float4 acc = make_float4(0.f, 0.f, 0.f, 0.f);
  if (beg < end) {
    int2 ec = csr[beg];
    uint2 rc = *((const uint2*)(s + (size_t)ec.x * 256) + lane);
    for (int i = beg + 1; i < end; ++i) {
      int2 en = csr[i];
      uint2 rn = *((const uint2*)(s + (size_t)en.x * 256) + lane);
      float val = __int_as_float(ec.y);
      float2 f0 = bf2_to_f2(rc.x), f1 = bf2_to_f2(rc.y);
      acc.x += val * f0.x; acc.y += val * f0.y;
      acc.z += val * f1.x; acc.w += val * f1.y;
      ec = en; rc = rn;
    }
    float val = __int_as_float(ec.y);
    float2 f0 = bf2_to_f2(rc.x), f1 = bf2_to_f2(rc.y);
    acc.x += val * f0.x; acc.y += val * f0.y;
    acc.z += val * f1.x; acc.w += val * f1.y;
  }
  uint2 o = make_uint2(f2_to_bf2(acc.x, acc.y), f2_to_bf2(acc.z, acc.w));
  *((uint2*)(h + (size_t)node * 256) + lane) = o;
}

__global__ __launch_bounds__(256) void spmm128_kernel(
    const int* __restrict__ rowptr, const int2* __restrict__ csr,
    const bf16_t* __restrict__ s, bf16_t* __restrict__ h) {
  int node = blockIdx.x * 4 + (threadIdx.x >> 6);
  int lane = threadIdx.x & 63;
  if (node >= N_NODES) return;
  int beg = rowptr[node], end = rowptr[node + 1];
  float2 acc = make_float2(0.f, 0.f);
  if (beg < end) {
    int2 ec = csr[beg];
    unsigned rc = *((const unsigned*)(s + (size_t)ec.x * 128) + lane);
    for (int i = beg + 1; i < end; ++i) {
      int2 en = csr[i];
      unsigned rn = *((const unsigned*)(s + (size_t)en.x * 128) + lane);
      float val = __int_as_float(ec.y);
      float2 f = bf2_to_f2(rc);
      acc.x += val * f.x; acc.y += val * f.y;
      ec = en; rc = rn;
    }
    float val = __int_as_float(ec.y);
    float2 f = bf2_to_f2(rc);
    acc.x += val * f.x; acc.y += val * f.y;
  }
  *((unsigned*)(h + (size_t)node * 128) + lane) = f2_to_bf2(acc.x, acc.y);
}

__global__ __launch_bounds__(256) void spmm40_kernel(
    const int* __restrict__ rowptr, const int2* __restrict__ csr,
    const bf16_t* __restrict__ s, float* __restrict__ out) {
  int node = blockIdx.x * 8 + (threadIdx.x >> 5);
  int l = threadIdx.x & 31;
  if (node >= N_NODES) return;
  bool active = (l < 20);
  int beg = rowptr[node], end = rowptr[node + 1];
  float2 acc = make_float2(0.f, 0.f);
  if (beg < end) {
    int2 ec = csr[beg];
    unsigned rc = active ? *((const unsigned*)(s + (size_t)ec.x * 40) + l) : 0u;
    for (int i = beg + 1; i < end; ++i) {
      int2 en = csr[i];
      unsigned rn = active ? *((const unsigned*)(s + (size_t)en.x * 40) + l) : 0u;
      float val = __int_as_float(ec.y);
      float2 f = bf2_to_f2(rc);
      acc.x += val * f.x; acc.y += val * f.y;
      ec = en; rc = rn;
    }
    float val = __int_as_float(ec.y);
    float2 f = bf2_to_f2(rc);
    acc.x += val * f.x; acc.y += val * f.y;
  }
  if (active) *((float2*)(out + (size_t)node * 40) + l) = acc;
}

// ---------------------------------------------------------------------------
// log_softmax over 40 classes; one wave per row, in-place fp32.
// ---------------------------------------------------------------------------
__global__ __launch_bounds__(256) void logsoftmax_kernel(float* __restrict__ io,
                                                         int M) {
  const int lane = threadIdx.x & 63;
  const int row = blockIdx.x * 4 + (threadIdx.x >> 6);
  if (row >= M) return;
  float v = (lane < 40) ? io[(size_t)row * 40 + lane] : -INFINITY;
  float m = v;
  #pragma unroll
  for (int off = 32; off > 0; off >>= 1)
    m = fmaxf(m, __shfl_xor(m, off));
  float ex = (lane < 40) ? __expf(v - m) : 0.f;
  float sum = ex;
  #pragma unroll
  for (int off = 32; off > 0; off >>= 1)
    sum += __shfl_xor(sum, off);
  if (lane < 40) io[(size_t)row * 40 + lane] = v - m - logf(sum);
}

// ---------------------------------------------------------------------------
extern "C" void kernel_launch(void* const* d_in, const int* in_sizes, int n_in,
                              void* d_out, int out_size, void* d_ws,
                              size_t ws_size, hipStream_t stream) {
  const float* x    = (const float*)d_in[0];
  const int*   esrc = (const int*)d_in[1];
  const int*   edst = (const int*)d_in[2];
  const float* eval = (const float*)d_in[3];
  const float* W0   = (const float*)d_in[4];
  const float* b0   = (const float*)d_in[5];
  const float* W1   = (const float*)d_in[6];
  const float* b1   = (const float*)d_in[7];
  const float* W2   = (const float*)d_in[8];
  const float* b2   = (const float*)d_in[9];
  float* out = (float*)d_out;

  char* ws = (char*)d_ws;
  bf16_t* bufA    = (bf16_t*)(ws + 0);            // 51.2 MB
  bf16_t* bufB    = (bf16_t*)(ws + 51200000);     // 51.2 MB
  int2*   csr     = (int2*)  (ws + 102400000);    // 25.6 MB
  int2*   tmp     = (int2*)  (ws + 128000000);    // 25.6 MB
  int*    rowptr  = (int*)   (ws + 153600000);    // 400,004 B
  int*    cntp    = (int*)   (ws + 154004480);    // 50,048 B (padded)
  int*    cursorp = (int*)   (ws + 154058752);    // 50,048 B (padded)
  int*    base    = (int*)   (ws + 154112000);    // 3,132 B
  unsigned short* Wt0 = (unsigned short*)(ws + 154120192);  // 262,144 B
  unsigned short* Wt1 = (unsigned short*)(ws + 154390528);  //  65,536 B
  unsigned short* Wt2 = (unsigned short*)(ws + 154460160);  //  10,240 B

  const int M = N_NODES;
  dim3 blk(256);

  // ---- CSR build: bucketed two-pass sort ----
  hipMemsetAsync(cntp, 0, NBUK * 64, stream);
  bucket_hist_kernel<<<NBUK, blk, 0, stream>>>(edst, cntp);
  scan_buckets_kernel<<<1, 1024, 0, stream>>>(cntp, base, cursorp, rowptr);
  bucket_scatter_kernel<<<(N_EDGES + 255) / 256, blk, 0, stream>>>(
      esrc, edst, eval, cursorp, tmp);
  sort_bucket_kernel<<<NBUK, blk, 0, stream>>>(base, tmp, csr, rowptr);

  // ---- W transposes (fp32 -> bf16, n-major) ----
  transpose_w_kernel<<<(512 * 256 + 255) / 256, blk, 0, stream>>>(W0, Wt0, 9, 256);
  transpose_w_kernel<<<(256 * 128 + 255) / 256, blk, 0, stream>>>(W1, Wt1, 8, 128);
  transpose_w_kernel<<<(128 * 40 + 255) / 256, blk, 0, stream>>>(W2, Wt2, 7, 40);

  const int MB = (M + 127) / 128;  // 782

  // ---- Layer 0: s0 = x @ W0 + b0  [100000 x 256] bf16 ----
  mfma_gemm_kernel<true, false><<<dim3(MB, 2), blk, 0, stream>>>(
      x, Wt0, b0, bufA, M, 512, 256);
  spmm256_kernel<<<25000, blk, 0, stream>>>(rowptr, csr, bufA, bufB);

  // ---- Layer 1: s1 = relu(h1) @ W1 + b1  [100000 x 128] bf16 ----
  mfma_gemm_kernel<false, true><<<dim3(MB, 1), blk, 0, stream>>>(
      bufB, Wt1, b1, bufA, M, 256, 128);
  spmm128_kernel<<<25000, blk, 0, stream>>>(rowptr, csr, bufA, bufB);

  // ---- Layer 2: s2 = relu(h2) @ W2 + b2  [100000 x 40] bf16 ----
  mfma_gemm_kernel<false, true><<<dim3(MB, 1), blk, 0, stream>>>(
      bufB, Wt2, b2, bufA, M, 128, 40);
  spmm40_kernel<<<12500, blk, 0, stream>>>(rowptr, csr, bufA, out);

  // ---- log_softmax in-place on d_out ----
  logsoftmax_kernel<<<25000, blk, 0, stream>>>(out, M);
}